// Round 8
// baseline (573.340 us; speedup 1.0000x reference)
//
#include <hip/hip_runtime.h>
#include <hip/hip_fp16.h>

// ---------------------------------------------------------------------------
// HyperbolicGNN: BN -> 6x EdgeConv -> centroid dist+pool (fused) -> FC
// fp16 datapath, f16 MFMA 16x16x32, fp32 accum.
// edge_agg: W2 fragments in registers; LDS = h1/h2 tile only.
// dist: fused with per-graph pooling (segmented scan over sorted gid ->
// atomicAdd psum) -- no N x 100 dist buffer materialized.
// ---------------------------------------------------------------------------
#define N_NODES 30000
#define N_EDGES 480000
#define N_GRAPHS 128
#define IN_FEAT 5
#define NUM_CENTROID 100
#define BN_EPS 1e-5f

typedef unsigned int u32;
typedef unsigned short u16;

using half8 = __attribute__((ext_vector_type(8))) _Float16;
using h2    = __attribute__((ext_vector_type(2))) _Float16;
using f32x4 = __attribute__((ext_vector_type(4))) float;

__device__ __forceinline__ u16 f2h(float x) {
    return __half_as_ushort(__float2half_rn(x));
}
__device__ __forceinline__ float h2f(u16 h) {
    return __half2float(__ushort_as_half(h));
}
__device__ __forceinline__ u32 pack2h(float lo, float hi) {
    return (u32)f2h(lo) | ((u32)f2h(hi) << 16);
}

// ---------------------------------------------------------------------------
// setup1: bn_stats [0,118) + dst histogram [118,118+1875) + gid histogram
// ---------------------------------------------------------------------------
#define BN_BLKS 118
#define DSTH_BLKS 1875
__global__ __launch_bounds__(256) void setup1_kernel(
    const float* __restrict__ f, float* __restrict__ acc,
    const int* __restrict__ dst, int* __restrict__ counts,
    const int* __restrict__ gid, int* __restrict__ gcnt)
{
    __shared__ float s[10];
    const int b = blockIdx.x;
    if (b < BN_BLKS) {
        if (threadIdx.x < 10) s[threadIdx.x] = 0.f;
        __syncthreads();
        int n = b * 256 + threadIdx.x;
        if (n < N_NODES) {
            #pragma unroll
            for (int k = 0; k < IN_FEAT; ++k) {
                float v = f[n * IN_FEAT + k];
                atomicAdd(&s[k], v);
                atomicAdd(&s[5 + k], v * v);
            }
        }
        __syncthreads();
        if (threadIdx.x < 10) atomicAdd(&acc[threadIdx.x], s[threadIdx.x]);
    } else if (b < BN_BLKS + DSTH_BLKS) {
        int e = (b - BN_BLKS) * 256 + threadIdx.x;
        if (e < N_EDGES) atomicAdd(&counts[dst[e]], 1);
    } else {
        int n = (b - BN_BLKS - DSTH_BLKS) * 256 + threadIdx.x;
        if (n < N_NODES) atomicAdd(&gcnt[gid[n]], 1);
    }
}

// ---------------------------------------------------------------------------
// scan: row offsets + deg_inv (single block)
// ---------------------------------------------------------------------------
__global__ __launch_bounds__(1024) void scan_kernel(
    const int* __restrict__ counts, int* __restrict__ row_off,
    float* __restrict__ deg_inv, int N)
{
    __shared__ int s[1024];
    const int CH = 30;
    int t = threadIdx.x;
    int base = t * CH;
    int loc = 0;
    for (int j = 0; j < CH; ++j) {
        int i = base + j;
        if (i < N) loc += counts[i];
    }
    s[t] = loc;
    __syncthreads();
    for (int off = 1; off < 1024; off <<= 1) {
        int v = (t >= off) ? s[t - off] : 0;
        __syncthreads();
        s[t] += v;
        __syncthreads();
    }
    int run = s[t] - loc;
    for (int j = 0; j < CH; ++j) {
        int i = base + j;
        if (i < N) {
            int cv = counts[i];
            row_off[i] = run;
            run += cv;
            deg_inv[i] = 1.0f / fmaxf((float)cv, 1.0f);
        }
    }
    if (t == 1023) row_off[N] = s[1023];
}

// ---------------------------------------------------------------------------
// setup2: csr_fill + bn_norm + megaprep (fp16 images, swizzled)
// ---------------------------------------------------------------------------
__constant__ __device__ const int LFIN[6] = {5, 32, 32, 64, 64, 128};
__constant__ __device__ const int LKD[6]  = {32, 32, 32, 64, 64, 128};
__constant__ __device__ const int LCD[6]  = {32, 32, 64, 64, 128, 128};
__constant__ __device__ const int W1OFF[6] = {0, 2048, 4096, 8192, 16384, 32768};
__constant__ __device__ const int W2OFF[6] = {0, 1024, 2048, 6144, 10240, 26624};
#define W1TOT 65536
#define W2TOT 43008
#define CTOT  14336  // 112*128
#define PREP_TOT (W1TOT + W2TOT + CTOT + 112)

#define CSR_BLKS 1875
#define BNN_BLKS 586

struct Setup2Args {
    const int* dst; const int* src; const int* row_off; int* cursor;
    int* csr_src; int* csr_dst;
    const float* f; const float* acc; const float* gamma; const float* beta;
    float* X0;
    const float* w1[6]; const float* w2[6]; const float* cent;
    u16* w1img; u16* w2img; u16* centimg; float* csq;
};

__global__ __launch_bounds__(256) void setup2_kernel(Setup2Args a)
{
    const int b = blockIdx.x;
    if (b < CSR_BLKS) {
        int e = b * 256 + threadIdx.x;
        if (e < N_EDGES) {
            int d = a.dst[e];
            int p = atomicAdd(&a.cursor[d], 1);
            a.csr_src[a.row_off[d] + p] = a.src[e];
            a.csr_dst[a.row_off[d] + p] = d;
        }
        return;
    }
    if (b < CSR_BLKS + BNN_BLKS) {
        int i = (b - CSR_BLKS) * 256 + threadIdx.x;
        if (i < N_NODES * IN_FEAT) {
            int k = i % IN_FEAT;
            float mu = a.acc[k] / (float)N_NODES;
            float var = a.acc[5 + k] / (float)N_NODES - mu * mu;
            float sc = a.gamma[k] / sqrtf(var + BN_EPS);
            a.X0[i] = (a.f[i] - mu) * sc + a.beta[k];
        }
        return;
    }
    int gid = (b - CSR_BLKS - BNN_BLKS) * 256 + threadIdx.x;
    if (gid < W1TOT) {
        int l = 0;
        #pragma unroll
        for (int i = 1; i < 6; ++i) if (gid >= W1OFF[i]) l = i;
        int local = gid - W1OFF[l];
        int K = LKD[l], C = LCD[l], F = LFIN[l];
        int n = local / K, k = local % K;
        float v = 0.f;
        if (k < F) {
            if (n < C) v = a.w1[l][k * C + n] - a.w1[l][(F + k) * C + n];
            else       v = a.w1[l][(F + k) * C + (n - C)];
        }
        int byte = (local * 2) ^ ((n & 7) << 4);
        *(u16*)((char*)a.w1img + (size_t)W1OFF[l] * 2 + byte) = f2h(v);
        return;
    }
    int g2 = gid - W1TOT;
    if (g2 < W2TOT) {
        int l = 0;
        #pragma unroll
        for (int i = 1; i < 6; ++i) if (g2 >= W2OFF[i]) l = i;
        int local = g2 - W2OFF[l];
        int C = LCD[l];
        int n = local / C, k = local % C;
        float v = a.w2[l][k * C + n];
        int byte = (local * 2) ^ ((n & 7) << 4);
        *(u16*)((char*)a.w2img + (size_t)W2OFF[l] * 2 + byte) = f2h(v);
        return;
    }
    int g3 = g2 - W2TOT;
    if (g3 < CTOT) {
        int c = g3 / 128, d = g3 % 128;
        float v = (c < NUM_CENTROID) ? a.cent[c * 128 + d] : 0.f;
        int byte = (g3 * 2) ^ ((c & 7) << 4);
        *(u16*)((char*)a.centimg + byte) = f2h(v);
        return;
    }
    int c = g3 - CTOT;
    if (c < 112) {
        float s = 0.f;
        if (c < NUM_CENTROID) {
            for (int d = 0; d < 128; ++d) {
                float cv = h2f(f2h(a.cent[c * 128 + d]));
                s += cv * cv;
            }
        }
        a.csq[c] = s;
    }
}

// ---------------------------------------------------------------------------
// Node MFMA GEMM: [32 nodes] x [2C cols], fp16 in/out, fp32 accum.
// ---------------------------------------------------------------------------
template <int FIN, int K, int C>
__global__ __launch_bounds__(256) void node_mfma_kernel(
    const float* __restrict__ Xin, const float* __restrict__ scale,
    const u16* __restrict__ w1img, const float* __restrict__ b1,
    u16* __restrict__ U, u16* __restrict__ V, int N)
{
    constexpr int COLS = 2 * C;
    __shared__ u16 wt[COLS * K];
    __shared__ u16 xt[32 * K];

    for (int i = threadIdx.x; i < COLS * K / 8; i += 256)
        reinterpret_cast<uint4*>(wt)[i] = reinterpret_cast<const uint4*>(w1img)[i];

    constexpr int DPT = K / 8;
    const int nl = threadIdx.x >> 3;
    const int part = threadIdx.x & 7;
    const int n = blockIdx.x * 32 + nl;
    const int k0 = part * DPT;
    const bool vld = (n < N);
    float s = 1.f;
    if (vld && scale) s = scale[n];

    float xv[DPT];
    if constexpr (FIN == K) {
        #pragma unroll
        for (int j4 = 0; j4 < DPT / 4; ++j4) {
            float4 f4 = {0, 0, 0, 0};
            if (vld) f4 = *reinterpret_cast<const float4*>(Xin + (size_t)n * FIN + k0 + j4 * 4);
            xv[j4 * 4 + 0] = f4.x * s; xv[j4 * 4 + 1] = f4.y * s;
            xv[j4 * 4 + 2] = f4.z * s; xv[j4 * 4 + 3] = f4.w * s;
        }
    } else {
        #pragma unroll
        for (int j = 0; j < DPT; ++j) {
            int k = k0 + j;
            xv[j] = (vld && k < FIN) ? Xin[(size_t)n * FIN + k] * s : 0.f;
        }
    }

    if constexpr (DPT == 4) {
        u32 o[2];
        o[0] = pack2h(xv[0], xv[1]);
        o[1] = pack2h(xv[2], xv[3]);
        int byte = ((nl * K + k0) * 2) ^ ((nl & 7) << 4);
        *reinterpret_cast<uint2*>((char*)xt + byte) = *reinterpret_cast<uint2*>(o);
    } else {
        #pragma unroll
        for (int j8 = 0; j8 < DPT / 8; ++j8) {
            u32 o[4];
            #pragma unroll
            for (int q = 0; q < 4; ++q)
                o[q] = pack2h(xv[j8 * 8 + q * 2], xv[j8 * 8 + q * 2 + 1]);
            int byte = ((nl * K + k0 + j8 * 8) * 2) ^ ((nl & 7) << 4);
            *reinterpret_cast<uint4*>((char*)xt + byte) = *reinterpret_cast<uint4*>(o);
        }
    }
    __syncthreads();

    constexpr int NT = COLS / 16;
    constexpr int NPW = NT / 4;   // 1, 2, 4
    constexpr int KS = K / 32;

    const int wid = threadIdx.x >> 6;
    const int lane = threadIdx.x & 63;
    const int lrow = lane & 15;
    const int lk8 = (lane >> 4) * 8;

    f32x4 acc[2][NPW] = {};

    #pragma unroll
    for (int ks = 0; ks < KS; ++ks) {
        half8 afrag[2];
        #pragma unroll
        for (int m = 0; m < 2; ++m) {
            int row = m * 16 + lrow;
            int byte = ((row * K + ks * 32 + lk8) * 2) ^ ((row & 7) << 4);
            afrag[m] = *reinterpret_cast<const half8*>((const char*)xt + byte);
        }
        #pragma unroll
        for (int nn = 0; nn < NPW; ++nn) {
            int colr = (wid * NPW + nn) * 16 + lrow;
            int byte = ((colr * K + ks * 32 + lk8) * 2) ^ ((colr & 7) << 4);
            half8 bfrag = *reinterpret_cast<const half8*>((const char*)wt + byte);
            #pragma unroll
            for (int m = 0; m < 2; ++m)
                acc[m][nn] = __builtin_amdgcn_mfma_f32_16x16x32_f16(
                    afrag[m], bfrag, acc[m][nn], 0, 0, 0);
        }
    }

    #pragma unroll
    for (int nn = 0; nn < NPW; ++nn) {
        int colr = (wid * NPW + nn) * 16 + lrow;
        float bias = (colr < C) ? b1[colr] : 0.f;
        #pragma unroll
        for (int m = 0; m < 2; ++m) {
            #pragma unroll
            for (int j = 0; j < 4; ++j) {
                int row = m * 16 + (lane >> 4) * 4 + j;
                int node = blockIdx.x * 32 + row;
                if (node < N) {
                    float z = acc[m][nn][j] + bias;
                    if (colr < C) U[(size_t)node * C + colr] = f2h(z);
                    else          V[(size_t)node * C + colr - C] = f2h(z);
                }
            }
        }
    }
}

// ---------------------------------------------------------------------------
// Fused edge GEMM + segmented reduction. W2 fragments in registers.
// ---------------------------------------------------------------------------
template <int C, int ET>
__global__ __launch_bounds__(256, 4) void edge_agg_kernel(
    const u16* __restrict__ U, const u16* __restrict__ V,
    const int* __restrict__ csr_src, const int* __restrict__ csr_dst,
    const u16* __restrict__ w2img, const float* __restrict__ b2,
    float* __restrict__ Xout, int E)
{
    constexpr int PAD = 2;
    __shared__ u16 at[ET * (C + PAD)];
    __shared__ int dstid[ET];

    constexpr int MT = ET / 16;
    constexpr int NT = C / 16;
    constexpr int WN = (NT < 4) ? NT : 4;
    constexpr int WM = 4 / WN;
    constexpr int MPW = MT / WM;
    constexpr int NPW = NT / WN;
    constexpr int KS = C / 32;

    const int wid = threadIdx.x >> 6;
    const int lane = threadIdx.x & 63;
    const int wn = wid % WN;
    const int wm = wid / WN;
    const int lrow = lane & 15;
    const int lk8 = (lane >> 4) * 8;

    half8 bfrag[NPW][KS];
    #pragma unroll
    for (int n = 0; n < NPW; ++n) {
        int col = (wn * NPW + n) * 16 + lrow;
        #pragma unroll
        for (int ks = 0; ks < KS; ++ks) {
            int byte = ((col * C + ks * 32 + lk8) * 2) ^ ((col & 7) << 4);
            bfrag[n][ks] = *reinterpret_cast<const half8*>((const char*)w2img + byte);
        }
    }

    constexpr int TPE = 256 / ET;
    const int e_loc = threadIdx.x / TPE;
    const int part  = threadIdx.x % TPE;
    const int k0 = part * 32;
    const int e = blockIdx.x * ET + e_loc;
    const bool valid = (e < E);
    const int dn = valid ? csr_dst[e] : 0;
    const int sn = valid ? csr_src[e] : 0;
    if (part == 0) dstid[e_loc] = valid ? dn : -1;

    const h2 zz = {(_Float16)0.f, (_Float16)0.f};
    const u16* Ur = U + (size_t)dn * C + k0;
    const u16* Vr = V + (size_t)sn * C + k0;
    #pragma unroll
    for (int j = 0; j < 4; ++j) {
        uint4 uu = {0, 0, 0, 0}, vv = {0, 0, 0, 0};
        if (valid) {
            uu = *reinterpret_cast<const uint4*>(Ur + j * 8);
            vv = *reinterpret_cast<const uint4*>(Vr + j * 8);
        }
        h2 o[4];
        const h2* ua = reinterpret_cast<const h2*>(&uu);
        const h2* va = reinterpret_cast<const h2*>(&vv);
        #pragma unroll
        for (int q = 0; q < 4; ++q)
            o[q] = __builtin_elementwise_max(ua[q] + va[q], zz);
        int byte = ((e_loc * C + k0 + j * 8) * 2) ^ ((e_loc & 7) << 4);
        *reinterpret_cast<uint4*>((char*)at + byte) = *reinterpret_cast<const uint4*>(o);
    }
    __syncthreads();

    f32x4 acc[MPW][NPW] = {};

    #pragma unroll
    for (int ks = 0; ks < KS; ++ks) {
        half8 afrag[MPW];
        #pragma unroll
        for (int m = 0; m < MPW; ++m) {
            int row = (wm * MPW + m) * 16 + lrow;
            int byte = ((row * C + ks * 32 + lk8) * 2) ^ ((row & 7) << 4);
            afrag[m] = *reinterpret_cast<const half8*>((const char*)at + byte);
        }
        #pragma unroll
        for (int m = 0; m < MPW; ++m)
            #pragma unroll
            for (int n = 0; n < NPW; ++n)
                acc[m][n] = __builtin_amdgcn_mfma_f32_16x16x32_f16(
                    afrag[m], bfrag[n][ks], acc[m][n], 0, 0, 0);
    }
    __syncthreads();

    #pragma unroll
    for (int m = 0; m < MPW; ++m) {
        #pragma unroll
        for (int n = 0; n < NPW; ++n) {
            int col = (wn * NPW + n) * 16 + lrow;
            float bb = b2[col];
            #pragma unroll
            for (int j = 0; j < 4; ++j) {
                int row = (wm * MPW + m) * 16 + (lane >> 4) * 4 + j;
                at[row * (C + PAD) + col] = f2h(fmaxf(acc[m][n][j] + bb, 0.f));
            }
        }
    }
    __syncthreads();

    constexpr int EPS = ET * C / 256;  // == 32
    const int col = threadIdx.x & (C - 1);
    const int e0 = (threadIdx.x / C) * EPS;
    float sum = 0.f;
    int cur = dstid[e0];
    #pragma unroll 4
    for (int ee = e0; ee < e0 + EPS; ++ee) {
        int d = dstid[ee];
        if (d != cur) {
            if (cur >= 0) atomicAdd(&Xout[(size_t)cur * C + col], sum);
            sum = 0.f;
            cur = d;
        }
        sum += h2f(at[ee * (C + PAD) + col]);
    }
    if (cur >= 0) atomicAdd(&Xout[(size_t)cur * C + col], sum);
}

// ---------------------------------------------------------------------------
// Fused centroid-distance + per-graph pooling.
// dist^2 = |x|^2 - 2 x.c + |c|^2 via MFMA; dist tile -> LDS (overlaying the
// dead centroid tile); segmented scan over sorted gid -> atomicAdd psum.
// ---------------------------------------------------------------------------
__global__ __launch_bounds__(256) void dist_pool_kernel(
    const float* __restrict__ X, const float* __restrict__ scale,
    const u16* __restrict__ centimg, const float* __restrict__ csq,
    const int* __restrict__ gid, float* __restrict__ psum, int N)
{
    // smem layout: [0,28672) ct (u16) later overlaid by dt (float 64x112)
    //              [28672,45056) xt  [45056,46080) xsqp  [46080,46528) csqs
    //              [46528,46784) gidS
    __shared__ char smem[46784];
    u16* ct = (u16*)smem;
    u16* xt = (u16*)(smem + 28672);
    float* xsqp = (float*)(smem + 45056);   // [64][4]
    float* csqs = (float*)(smem + 46080);   // [112]
    int* gidS   = (int*)(smem + 46528);     // [64]
    float* dt   = (float*)smem;             // [64][112], overlays ct

    for (int i = threadIdx.x; i < 112 * 128 / 8; i += 256)
        reinterpret_cast<uint4*>(ct)[i] = reinterpret_cast<const uint4*>(centimg)[i];
    if (threadIdx.x < 112) csqs[threadIdx.x] = csq[threadIdx.x];
    if (threadIdx.x < 64) {
        int n = blockIdx.x * 64 + threadIdx.x;
        gidS[threadIdx.x] = (n < N) ? gid[n] : -1;
    }

    const int nl = threadIdx.x >> 2;
    const int part = threadIdx.x & 3;
    const int n = blockIdx.x * 64 + nl;
    const int k0 = part * 32;
    const bool vld = (n < N);
    const float s = vld ? scale[n] : 0.f;

    float ss = 0.f;
    #pragma unroll
    for (int j8 = 0; j8 < 4; ++j8) {
        float4 f0 = {0, 0, 0, 0}, f1 = {0, 0, 0, 0};
        if (vld) {
            f0 = *reinterpret_cast<const float4*>(X + (size_t)n * 128 + k0 + j8 * 8);
            f1 = *reinterpret_cast<const float4*>(X + (size_t)n * 128 + k0 + j8 * 8 + 4);
        }
        float xv[8] = {f0.x * s, f0.y * s, f0.z * s, f0.w * s,
                       f1.x * s, f1.y * s, f1.z * s, f1.w * s};
        u32 o[4];
        #pragma unroll
        for (int q = 0; q < 4; ++q) {
            float lo = h2f(f2h(xv[q * 2]));
            float hi = h2f(f2h(xv[q * 2 + 1]));
            ss += lo * lo + hi * hi;
            o[q] = pack2h(xv[q * 2], xv[q * 2 + 1]);
        }
        int byte = ((nl * 128 + k0 + j8 * 8) * 2) ^ ((nl & 7) << 4);
        *reinterpret_cast<uint4*>((char*)xt + byte) = *reinterpret_cast<uint4*>(o);
    }
    xsqp[nl * 4 + part] = ss;
    __syncthreads();

    const int wid = threadIdx.x >> 6;
    const int lane = threadIdx.x & 63;
    const int lrow = lane & 15;
    const int lk8 = (lane >> 4) * 8;

    f32x4 acc[7] = {};
    #pragma unroll
    for (int ks = 0; ks < 4; ++ks) {
        int row = wid * 16 + lrow;
        int byte = ((row * 128 + ks * 32 + lk8) * 2) ^ ((row & 7) << 4);
        half8 afrag = *reinterpret_cast<const half8*>((const char*)xt + byte);
        #pragma unroll
        for (int nn = 0; nn < 7; ++nn) {
            int colr = nn * 16 + lrow;
            int bb = ((colr * 128 + ks * 32 + lk8) * 2) ^ ((colr & 7) << 4);
            half8 bfrag = *reinterpret_cast<const half8*>((const char*)ct + bb);
            acc[nn] = __builtin_amdgcn_mfma_f32_16x16x32_f16(afrag, bfrag, acc[nn], 0, 0, 0);
        }
    }

    float xs[4];
    #pragma unroll
    for (int j = 0; j < 4; ++j) {
        int row = wid * 16 + (lane >> 4) * 4 + j;
        xs[j] = xsqp[row * 4 + 0] + xsqp[row * 4 + 1] + xsqp[row * 4 + 2] + xsqp[row * 4 + 3];
    }
    __syncthreads();  // all waves done reading ct -> safe to overlay with dt

    #pragma unroll
    for (int nn = 0; nn < 7; ++nn) {
        int colr = nn * 16 + lrow;
        float cq = csqs[colr];
        #pragma unroll
        for (int j = 0; j < 4; ++j) {
            int row = wid * 16 + (lane >> 4) * 4 + j;
            float v = xs[j] - 2.f * acc[nn][j] + cq;
            dt[row * 112 + colr] = sqrtf(fmaxf(v, 0.f) + 1e-12f);
        }
    }
    __syncthreads();

    // segmented scan over 64 sorted gids, one column per thread
    if (threadIdx.x < NUM_CENTROID) {
        const int col = threadIdx.x;
        float sum = 0.f;
        int cur = gidS[0];
        for (int r = 0; r < 64; ++r) {
            int g = gidS[r];
            if (g != cur) {
                if (cur >= 0) atomicAdd(&psum[cur * NUM_CENTROID + col], sum);
                sum = 0.f;
                cur = g;
            }
            if (g >= 0) sum += dt[r * 112 + col];
        }
        if (cur >= 0) atomicAdd(&psum[cur * NUM_CENTROID + col], sum);
    }
}

// ---------------------------------------------------------------------------
// Final FC: out[g][cls] = fc_b[cls] + (1/max(cnt_g,1)) * sum_c psum[g][c]*fc_w[c][cls]
// One 256-thread block: thread t -> (g = t>>1, cls = t&1).
// ---------------------------------------------------------------------------
__global__ __launch_bounds__(256) void fc_kernel(
    const float* __restrict__ psum, const int* __restrict__ gcnt,
    const float* __restrict__ fc_w, const float* __restrict__ fc_b,
    float* __restrict__ out)
{
    const int g = threadIdx.x >> 1;
    const int cls = threadIdx.x & 1;
    float o = 0.f;
    for (int c = 0; c < NUM_CENTROID; ++c)
        o += psum[g * NUM_CENTROID + c] * fc_w[c * 2 + cls];
    float cnt = fmaxf((float)gcnt[g], 1.0f);
    out[g * 2 + cls] = fc_b[cls] + o / cnt;
}

// ---------------------------------------------------------------------------
// Host launch
// ---------------------------------------------------------------------------
static const int W1OFF_H[6] = {0, 2048, 4096, 8192, 16384, 32768};
static const int W2OFF_H[6] = {0, 1024, 2048, 6144, 10240, 26624};

extern "C" void kernel_launch(void* const* d_in, const int* in_sizes, int n_in,
                              void* d_out, int out_size, void* d_ws, size_t ws_size,
                              hipStream_t stream) {
    const float* features = (const float*)d_in[0];
    const int*   src      = (const int*)d_in[1];
    const int*   dst      = (const int*)d_in[2];
    const int*   gid      = (const int*)d_in[3];
    const float* gamma    = (const float*)d_in[4];
    const float* beta     = (const float*)d_in[5];
    const float *W1[6], *b1[6], *W2[6], *b2[6];
    for (int i = 0; i < 6; ++i) {
        W1[i] = (const float*)d_in[6 + 4 * i];
        b1[i] = (const float*)d_in[7 + 4 * i];
        W2[i] = (const float*)d_in[8 + 4 * i];
        b2[i] = (const float*)d_in[9 + 4 * i];
    }
    const float* centroids = (const float*)d_in[30];
    const float* fc_w      = (const float*)d_in[31];
    const float* fc_b      = (const float*)d_in[32];

    const int N = N_NODES, E = N_EDGES;

    char* p = (char*)d_ws;
    size_t off = 0;
    auto alloc = [&](size_t bytes) {
        void* r = p + off;
        off += (bytes + 255) & ~(size_t)255;
        return r;
    };

    float* X0bn = (float*)alloc((size_t)N * IN_FEAT * 4);
    char* xz0 = p + off;
    float* XL[6];
    const int LCC[6] = {32, 32, 64, 64, 128, 128};
    for (int i = 0; i < 6; ++i) XL[i] = (float*)alloc((size_t)N * LCC[i] * 4);
    size_t xzbytes = (size_t)((p + off) - xz0);

    u16* Uh = (u16*)alloc((size_t)N * 128 * 2);
    u16* Vh = (u16*)alloc((size_t)N * 128 * 2);

    int*   row_off = (int*)alloc((size_t)(N + 1) * 4);
    int*   csr_src = (int*)alloc((size_t)E * 4);
    int*   csr_dst = (int*)alloc((size_t)E * 4);
    float* deg_inv = (float*)alloc((size_t)N * 4);
    u16*   w1img   = (u16*)alloc((size_t)W1TOT * 2);
    u16*   w2img   = (u16*)alloc((size_t)W2TOT * 2);
    u16*   centimg = (u16*)alloc((size_t)CTOT * 2);
    float* csq     = (float*)alloc(112 * 4);

    char*  zero0   = (char*)(p + off);
    int*   counts  = (int*)alloc((size_t)N * 4);
    int*   cursor  = (int*)alloc((size_t)N * 4);
    float* bnacc   = (float*)alloc(64);
    float* psum    = (float*)alloc((size_t)N_GRAPHS * NUM_CENTROID * 4);
    int*   gcnt    = (int*)alloc((size_t)N_GRAPHS * 4);
    size_t zbytes  = (size_t)((char*)(p + off) - zero0);

    (void)hipMemsetAsync(xz0, 0, xzbytes, stream);
    (void)hipMemsetAsync(zero0, 0, zbytes, stream);

    setup1_kernel<<<BN_BLKS + DSTH_BLKS + BN_BLKS, 256, 0, stream>>>(
        features, bnacc, dst, counts, gid, gcnt);
    scan_kernel<<<1, 1024, 0, stream>>>(counts, row_off, deg_inv, N);

    Setup2Args sa;
    sa.dst = dst; sa.src = src; sa.row_off = row_off; sa.cursor = cursor;
    sa.csr_src = csr_src; sa.csr_dst = csr_dst;
    sa.f = features; sa.acc = bnacc; sa.gamma = gamma; sa.beta = beta; sa.X0 = X0bn;
    for (int i = 0; i < 6; ++i) { sa.w1[i] = W1[i]; sa.w2[i] = W2[i]; }
    sa.cent = centroids; sa.w1img = w1img; sa.w2img = w2img;
    sa.centimg = centimg; sa.csq = csq;
    const int S2B = CSR_BLKS + BNN_BLKS + (PREP_TOT + 255) / 256;
    setup2_kernel<<<S2B, 256, 0, stream>>>(sa);

    const int NB = (N + 31) / 32;

    node_mfma_kernel<5, 32, 32><<<NB, 256, 0, stream>>>(
        X0bn, (const float*)nullptr, w1img + W1OFF_H[0], b1[0], Uh, Vh, N);
    edge_agg_kernel<32, 256><<<(E + 255) / 256, 256, 0, stream>>>(
        Uh, Vh, csr_src, csr_dst, w2img + W2OFF_H[0], b2[0], XL[0], E);

    node_mfma_kernel<32, 32, 32><<<NB, 256, 0, stream>>>(
        XL[0], deg_inv, w1img + W1OFF_H[1], b1[1], Uh, Vh, N);
    edge_agg_kernel<32, 256><<<(E + 255) / 256, 256, 0, stream>>>(
        Uh, Vh, csr_src, csr_dst, w2img + W2OFF_H[1], b2[1], XL[1], E);

    node_mfma_kernel<32, 32, 64><<<NB, 256, 0, stream>>>(
        XL[1], deg_inv, w1img + W1OFF_H[2], b1[2], Uh, Vh, N);
    edge_agg_kernel<64, 128><<<(E + 127) / 128, 256, 0, stream>>>(
        Uh, Vh, csr_src, csr_dst, w2img + W2OFF_H[2], b2[2], XL[2], E);

    node_mfma_kernel<64, 64, 64><<<NB, 256, 0, stream>>>(
        XL[2], deg_inv, w1img + W1OFF_H[3], b1[3], Uh, Vh, N);
    edge_agg_kernel<64, 128><<<(E + 127) / 128, 256, 0, stream>>>(
        Uh, Vh, csr_src, csr_dst, w2img + W2OFF_H[3], b2[3], XL[3], E);

    node_mfma_kernel<64, 64, 128><<<NB, 256, 0, stream>>>(
        XL[3], deg_inv, w1img + W1OFF_H[4], b1[4], Uh, Vh, N);
    edge_agg_kernel<128, 64><<<(E + 63) / 64, 256, 0, stream>>>(
        Uh, Vh, csr_src, csr_dst, w2img + W2OFF_H[4], b2[4], XL[4], E);

    node_mfma_kernel<128, 128, 128><<<NB, 256, 0, stream>>>(
        XL[4], deg_inv, w1img + W1OFF_H[5], b1[5], Uh, Vh, N);
    edge_agg_kernel<128, 64><<<(E + 63) / 64, 256, 0, stream>>>(
        Uh, Vh, csr_src, csr_dst, w2img + W2OFF_H[5], b2[5], XL[5], E);

    dist_pool_kernel<<<(N + 63) / 64, 256, 0, stream>>>(
        XL[5], deg_inv, centimg, csq, gid, psum, N);
    fc_kernel<<<1, 256, 0, stream>>>(psum, gcnt, fc_w, fc_b, (float*)d_out);
}

// Round 9
// 548.326 us; speedup vs baseline: 1.0456x; 1.0456x over previous
//
#include <hip/hip_runtime.h>
#include <hip/hip_fp16.h>

// ---------------------------------------------------------------------------
// HyperbolicGNN: BN -> 6x EdgeConv -> centroid dist+pool (fused) -> FC
// fp16 datapath, f16 MFMA 16x16x32, fp32 accum.
// edge_agg: W2 fragments in registers; LDS = h1/h2 tile only.
// dist: fused with per-graph pooling (segmented scan -> atomicAdd psum).
// setup1: BN stats via shfl-reduce (no LDS same-address atomics);
//         graph counts via binary search in fc (sorted gid), not histogram.
// ---------------------------------------------------------------------------
#define N_NODES 30000
#define N_EDGES 480000
#define N_GRAPHS 128
#define IN_FEAT 5
#define NUM_CENTROID 100
#define BN_EPS 1e-5f

typedef unsigned int u32;
typedef unsigned short u16;

using half8 = __attribute__((ext_vector_type(8))) _Float16;
using h2    = __attribute__((ext_vector_type(2))) _Float16;
using f32x4 = __attribute__((ext_vector_type(4))) float;

__device__ __forceinline__ u16 f2h(float x) {
    return __half_as_ushort(__float2half_rn(x));
}
__device__ __forceinline__ float h2f(u16 h) {
    return __half2float(__ushort_as_half(h));
}
__device__ __forceinline__ u32 pack2h(float lo, float hi) {
    return (u32)f2h(lo) | ((u32)f2h(hi) << 16);
}

// ---------------------------------------------------------------------------
// setup1: bn_stats via wave shfl-reduce [0,118) + dst histogram [118,1993)
// ---------------------------------------------------------------------------
#define BN_BLKS 118
#define DSTH_BLKS 1875
__global__ __launch_bounds__(256) void setup1_kernel(
    const float* __restrict__ f, float* __restrict__ acc,
    const int* __restrict__ dst, int* __restrict__ counts)
{
    const int b = blockIdx.x;
    if (b < BN_BLKS) {
        int n = b * 256 + threadIdx.x;
        float q[10];
        #pragma unroll
        for (int k = 0; k < 10; ++k) q[k] = 0.f;
        if (n < N_NODES) {
            #pragma unroll
            for (int k = 0; k < IN_FEAT; ++k) {
                float v = f[n * IN_FEAT + k];
                q[k] = v;
                q[5 + k] = v * v;
            }
        }
        #pragma unroll
        for (int k = 0; k < 10; ++k) {
            #pragma unroll
            for (int o = 32; o > 0; o >>= 1)
                q[k] += __shfl_xor(q[k], o);
        }
        if ((threadIdx.x & 63) == 0) {
            #pragma unroll
            for (int k = 0; k < 10; ++k) atomicAdd(&acc[k], q[k]);
        }
    } else {
        int e = (b - BN_BLKS) * 256 + threadIdx.x;
        if (e < N_EDGES) atomicAdd(&counts[dst[e]], 1);
    }
}

// ---------------------------------------------------------------------------
// scan: row offsets + deg_inv (single block)
// ---------------------------------------------------------------------------
__global__ __launch_bounds__(1024) void scan_kernel(
    const int* __restrict__ counts, int* __restrict__ row_off,
    float* __restrict__ deg_inv, int N)
{
    __shared__ int s[1024];
    const int CH = 30;
    int t = threadIdx.x;
    int base = t * CH;
    int loc = 0;
    for (int j = 0; j < CH; ++j) {
        int i = base + j;
        if (i < N) loc += counts[i];
    }
    s[t] = loc;
    __syncthreads();
    for (int off = 1; off < 1024; off <<= 1) {
        int v = (t >= off) ? s[t - off] : 0;
        __syncthreads();
        s[t] += v;
        __syncthreads();
    }
    int run = s[t] - loc;
    for (int j = 0; j < CH; ++j) {
        int i = base + j;
        if (i < N) {
            int cv = counts[i];
            row_off[i] = run;
            run += cv;
            deg_inv[i] = 1.0f / fmaxf((float)cv, 1.0f);
        }
    }
    if (t == 1023) row_off[N] = s[1023];
}

// ---------------------------------------------------------------------------
// setup2: csr_fill + bn_norm + megaprep (fp16 images, swizzled)
// ---------------------------------------------------------------------------
__constant__ __device__ const int LFIN[6] = {5, 32, 32, 64, 64, 128};
__constant__ __device__ const int LKD[6]  = {32, 32, 32, 64, 64, 128};
__constant__ __device__ const int LCD[6]  = {32, 32, 64, 64, 128, 128};
__constant__ __device__ const int W1OFF[6] = {0, 2048, 4096, 8192, 16384, 32768};
__constant__ __device__ const int W2OFF[6] = {0, 1024, 2048, 6144, 10240, 26624};
#define W1TOT 65536
#define W2TOT 43008
#define CTOT  14336  // 112*128
#define PREP_TOT (W1TOT + W2TOT + CTOT + 112)

#define CSR_BLKS 1875
#define BNN_BLKS 586

struct Setup2Args {
    const int* dst; const int* src; const int* row_off; int* cursor;
    int* csr_src; int* csr_dst;
    const float* f; const float* acc; const float* gamma; const float* beta;
    float* X0;
    const float* w1[6]; const float* w2[6]; const float* cent;
    u16* w1img; u16* w2img; u16* centimg; float* csq;
};

__global__ __launch_bounds__(256) void setup2_kernel(Setup2Args a)
{
    const int b = blockIdx.x;
    if (b < CSR_BLKS) {
        int e = b * 256 + threadIdx.x;
        if (e < N_EDGES) {
            int d = a.dst[e];
            int p = atomicAdd(&a.cursor[d], 1);
            a.csr_src[a.row_off[d] + p] = a.src[e];
            a.csr_dst[a.row_off[d] + p] = d;
        }
        return;
    }
    if (b < CSR_BLKS + BNN_BLKS) {
        int i = (b - CSR_BLKS) * 256 + threadIdx.x;
        if (i < N_NODES * IN_FEAT) {
            int k = i % IN_FEAT;
            float mu = a.acc[k] / (float)N_NODES;
            float var = a.acc[5 + k] / (float)N_NODES - mu * mu;
            float sc = a.gamma[k] / sqrtf(var + BN_EPS);
            a.X0[i] = (a.f[i] - mu) * sc + a.beta[k];
        }
        return;
    }
    int gid = (b - CSR_BLKS - BNN_BLKS) * 256 + threadIdx.x;
    if (gid < W1TOT) {
        int l = 0;
        #pragma unroll
        for (int i = 1; i < 6; ++i) if (gid >= W1OFF[i]) l = i;
        int local = gid - W1OFF[l];
        int K = LKD[l], C = LCD[l], F = LFIN[l];
        int n = local / K, k = local % K;
        float v = 0.f;
        if (k < F) {
            if (n < C) v = a.w1[l][k * C + n] - a.w1[l][(F + k) * C + n];
            else       v = a.w1[l][(F + k) * C + (n - C)];
        }
        int byte = (local * 2) ^ ((n & 7) << 4);
        *(u16*)((char*)a.w1img + (size_t)W1OFF[l] * 2 + byte) = f2h(v);
        return;
    }
    int g2 = gid - W1TOT;
    if (g2 < W2TOT) {
        int l = 0;
        #pragma unroll
        for (int i = 1; i < 6; ++i) if (g2 >= W2OFF[i]) l = i;
        int local = g2 - W2OFF[l];
        int C = LCD[l];
        int n = local / C, k = local % C;
        float v = a.w2[l][k * C + n];
        int byte = (local * 2) ^ ((n & 7) << 4);
        *(u16*)((char*)a.w2img + (size_t)W2OFF[l] * 2 + byte) = f2h(v);
        return;
    }
    int g3 = g2 - W2TOT;
    if (g3 < CTOT) {
        int c = g3 / 128, d = g3 % 128;
        float v = (c < NUM_CENTROID) ? a.cent[c * 128 + d] : 0.f;
        int byte = (g3 * 2) ^ ((c & 7) << 4);
        *(u16*)((char*)a.centimg + byte) = f2h(v);
        return;
    }
    int c = g3 - CTOT;
    if (c < 112) {
        float s = 0.f;
        if (c < NUM_CENTROID) {
            for (int d = 0; d < 128; ++d) {
                float cv = h2f(f2h(a.cent[c * 128 + d]));
                s += cv * cv;
            }
        }
        a.csq[c] = s;
    }
}

// ---------------------------------------------------------------------------
// Node MFMA GEMM: [32 nodes] x [2C cols], fp16 in/out, fp32 accum.
// ---------------------------------------------------------------------------
template <int FIN, int K, int C>
__global__ __launch_bounds__(256) void node_mfma_kernel(
    const float* __restrict__ Xin, const float* __restrict__ scale,
    const u16* __restrict__ w1img, const float* __restrict__ b1,
    u16* __restrict__ U, u16* __restrict__ V, int N)
{
    constexpr int COLS = 2 * C;
    __shared__ u16 wt[COLS * K];
    __shared__ u16 xt[32 * K];

    for (int i = threadIdx.x; i < COLS * K / 8; i += 256)
        reinterpret_cast<uint4*>(wt)[i] = reinterpret_cast<const uint4*>(w1img)[i];

    constexpr int DPT = K / 8;
    const int nl = threadIdx.x >> 3;
    const int part = threadIdx.x & 7;
    const int n = blockIdx.x * 32 + nl;
    const int k0 = part * DPT;
    const bool vld = (n < N);
    float s = 1.f;
    if (vld && scale) s = scale[n];

    float xv[DPT];
    if constexpr (FIN == K) {
        #pragma unroll
        for (int j4 = 0; j4 < DPT / 4; ++j4) {
            float4 f4 = {0, 0, 0, 0};
            if (vld) f4 = *reinterpret_cast<const float4*>(Xin + (size_t)n * FIN + k0 + j4 * 4);
            xv[j4 * 4 + 0] = f4.x * s; xv[j4 * 4 + 1] = f4.y * s;
            xv[j4 * 4 + 2] = f4.z * s; xv[j4 * 4 + 3] = f4.w * s;
        }
    } else {
        #pragma unroll
        for (int j = 0; j < DPT; ++j) {
            int k = k0 + j;
            xv[j] = (vld && k < FIN) ? Xin[(size_t)n * FIN + k] * s : 0.f;
        }
    }

    if constexpr (DPT == 4) {
        u32 o[2];
        o[0] = pack2h(xv[0], xv[1]);
        o[1] = pack2h(xv[2], xv[3]);
        int byte = ((nl * K + k0) * 2) ^ ((nl & 7) << 4);
        *reinterpret_cast<uint2*>((char*)xt + byte) = *reinterpret_cast<uint2*>(o);
    } else {
        #pragma unroll
        for (int j8 = 0; j8 < DPT / 8; ++j8) {
            u32 o[4];
            #pragma unroll
            for (int q = 0; q < 4; ++q)
                o[q] = pack2h(xv[j8 * 8 + q * 2], xv[j8 * 8 + q * 2 + 1]);
            int byte = ((nl * K + k0 + j8 * 8) * 2) ^ ((nl & 7) << 4);
            *reinterpret_cast<uint4*>((char*)xt + byte) = *reinterpret_cast<uint4*>(o);
        }
    }
    __syncthreads();

    constexpr int NT = COLS / 16;
    constexpr int NPW = NT / 4;   // 1, 2, 4
    constexpr int KS = K / 32;

    const int wid = threadIdx.x >> 6;
    const int lane = threadIdx.x & 63;
    const int lrow = lane & 15;
    const int lk8 = (lane >> 4) * 8;

    f32x4 acc[2][NPW] = {};

    #pragma unroll
    for (int ks = 0; ks < KS; ++ks) {
        half8 afrag[2];
        #pragma unroll
        for (int m = 0; m < 2; ++m) {
            int row = m * 16 + lrow;
            int byte = ((row * K + ks * 32 + lk8) * 2) ^ ((row & 7) << 4);
            afrag[m] = *reinterpret_cast<const half8*>((const char*)xt + byte);
        }
        #pragma unroll
        for (int nn = 0; nn < NPW; ++nn) {
            int colr = (wid * NPW + nn) * 16 + lrow;
            int byte = ((colr * K + ks * 32 + lk8) * 2) ^ ((colr & 7) << 4);
            half8 bfrag = *reinterpret_cast<const half8*>((const char*)wt + byte);
            #pragma unroll
            for (int m = 0; m < 2; ++m)
                acc[m][nn] = __builtin_amdgcn_mfma_f32_16x16x32_f16(
                    afrag[m], bfrag, acc[m][nn], 0, 0, 0);
        }
    }

    #pragma unroll
    for (int nn = 0; nn < NPW; ++nn) {
        int colr = (wid * NPW + nn) * 16 + lrow;
        float bias = (colr < C) ? b1[colr] : 0.f;
        #pragma unroll
        for (int m = 0; m < 2; ++m) {
            #pragma unroll
            for (int j = 0; j < 4; ++j) {
                int row = m * 16 + (lane >> 4) * 4 + j;
                int node = blockIdx.x * 32 + row;
                if (node < N) {
                    float z = acc[m][nn][j] + bias;
                    if (colr < C) U[(size_t)node * C + colr] = f2h(z);
                    else          V[(size_t)node * C + colr - C] = f2h(z);
                }
            }
        }
    }
}

// ---------------------------------------------------------------------------
// Fused edge GEMM + segmented reduction. W2 fragments in registers.
// ---------------------------------------------------------------------------
template <int C, int ET>
__global__ __launch_bounds__(256, 4) void edge_agg_kernel(
    const u16* __restrict__ U, const u16* __restrict__ V,
    const int* __restrict__ csr_src, const int* __restrict__ csr_dst,
    const u16* __restrict__ w2img, const float* __restrict__ b2,
    float* __restrict__ Xout, int E)
{
    constexpr int PAD = 2;
    __shared__ u16 at[ET * (C + PAD)];
    __shared__ int dstid[ET];

    constexpr int MT = ET / 16;
    constexpr int NT = C / 16;
    constexpr int WN = (NT < 4) ? NT : 4;
    constexpr int WM = 4 / WN;
    constexpr int MPW = MT / WM;
    constexpr int NPW = NT / WN;
    constexpr int KS = C / 32;

    const int wid = threadIdx.x >> 6;
    const int lane = threadIdx.x & 63;
    const int wn = wid % WN;
    const int wm = wid / WN;
    const int lrow = lane & 15;
    const int lk8 = (lane >> 4) * 8;

    half8 bfrag[NPW][KS];
    #pragma unroll
    for (int n = 0; n < NPW; ++n) {
        int col = (wn * NPW + n) * 16 + lrow;
        #pragma unroll
        for (int ks = 0; ks < KS; ++ks) {
            int byte = ((col * C + ks * 32 + lk8) * 2) ^ ((col & 7) << 4);
            bfrag[n][ks] = *reinterpret_cast<const half8*>((const char*)w2img + byte);
        }
    }

    constexpr int TPE = 256 / ET;
    const int e_loc = threadIdx.x / TPE;
    const int part  = threadIdx.x % TPE;
    const int k0 = part * 32;
    const int e = blockIdx.x * ET + e_loc;
    const bool valid = (e < E);
    const int dn = valid ? csr_dst[e] : 0;
    const int sn = valid ? csr_src[e] : 0;
    if (part == 0) dstid[e_loc] = valid ? dn : -1;

    const h2 zz = {(_Float16)0.f, (_Float16)0.f};
    const u16* Ur = U + (size_t)dn * C + k0;
    const u16* Vr = V + (size_t)sn * C + k0;
    #pragma unroll
    for (int j = 0; j < 4; ++j) {
        uint4 uu = {0, 0, 0, 0}, vv = {0, 0, 0, 0};
        if (valid) {
            uu = *reinterpret_cast<const uint4*>(Ur + j * 8);
            vv = *reinterpret_cast<const uint4*>(Vr + j * 8);
        }
        h2 o[4];
        const h2* ua = reinterpret_cast<const h2*>(&uu);
        const h2* va = reinterpret_cast<const h2*>(&vv);
        #pragma unroll
        for (int q = 0; q < 4; ++q)
            o[q] = __builtin_elementwise_max(ua[q] + va[q], zz);
        int byte = ((e_loc * C + k0 + j * 8) * 2) ^ ((e_loc & 7) << 4);
        *reinterpret_cast<uint4*>((char*)at + byte) = *reinterpret_cast<const uint4*>(o);
    }
    __syncthreads();

    f32x4 acc[MPW][NPW] = {};

    #pragma unroll
    for (int ks = 0; ks < KS; ++ks) {
        half8 afrag[MPW];
        #pragma unroll
        for (int m = 0; m < MPW; ++m) {
            int row = (wm * MPW + m) * 16 + lrow;
            int byte = ((row * C + ks * 32 + lk8) * 2) ^ ((row & 7) << 4);
            afrag[m] = *reinterpret_cast<const half8*>((const char*)at + byte);
        }
        #pragma unroll
        for (int m = 0; m < MPW; ++m)
            #pragma unroll
            for (int n = 0; n < NPW; ++n)
                acc[m][n] = __builtin_amdgcn_mfma_f32_16x16x32_f16(
                    afrag[m], bfrag[n][ks], acc[m][n], 0, 0, 0);
    }
    __syncthreads();

    #pragma unroll
    for (int m = 0; m < MPW; ++m) {
        #pragma unroll
        for (int n = 0; n < NPW; ++n) {
            int col = (wn * NPW + n) * 16 + lrow;
            float bb = b2[col];
            #pragma unroll
            for (int j = 0; j < 4; ++j) {
                int row = (wm * MPW + m) * 16 + (lane >> 4) * 4 + j;
                at[row * (C + PAD) + col] = f2h(fmaxf(acc[m][n][j] + bb, 0.f));
            }
        }
    }
    __syncthreads();

    constexpr int EPS = ET * C / 256;  // == 32
    const int col = threadIdx.x & (C - 1);
    const int e0 = (threadIdx.x / C) * EPS;
    float sum = 0.f;
    int cur = dstid[e0];
    #pragma unroll 4
    for (int ee = e0; ee < e0 + EPS; ++ee) {
        int d = dstid[ee];
        if (d != cur) {
            if (cur >= 0) atomicAdd(&Xout[(size_t)cur * C + col], sum);
            sum = 0.f;
            cur = d;
        }
        sum += h2f(at[ee * (C + PAD) + col]);
    }
    if (cur >= 0) atomicAdd(&Xout[(size_t)cur * C + col], sum);
}

// ---------------------------------------------------------------------------
// Fused centroid-distance + per-graph pooling.
// ---------------------------------------------------------------------------
__global__ __launch_bounds__(256) void dist_pool_kernel(
    const float* __restrict__ X, const float* __restrict__ scale,
    const u16* __restrict__ centimg, const float* __restrict__ csq,
    const int* __restrict__ gid, float* __restrict__ psum, int N)
{
    __shared__ char smem[46784];
    u16* ct = (u16*)smem;
    u16* xt = (u16*)(smem + 28672);
    float* xsqp = (float*)(smem + 45056);   // [64][4]
    float* csqs = (float*)(smem + 46080);   // [112]
    int* gidS   = (int*)(smem + 46528);     // [64]
    float* dt   = (float*)smem;             // [64][112], overlays ct

    for (int i = threadIdx.x; i < 112 * 128 / 8; i += 256)
        reinterpret_cast<uint4*>(ct)[i] = reinterpret_cast<const uint4*>(centimg)[i];
    if (threadIdx.x < 112) csqs[threadIdx.x] = csq[threadIdx.x];
    if (threadIdx.x < 64) {
        int n = blockIdx.x * 64 + threadIdx.x;
        gidS[threadIdx.x] = (n < N) ? gid[n] : -1;
    }

    const int nl = threadIdx.x >> 2;
    const int part = threadIdx.x & 3;
    const int n = blockIdx.x * 64 + nl;
    const int k0 = part * 32;
    const bool vld = (n < N);
    const float s = vld ? scale[n] : 0.f;

    float ss = 0.f;
    #pragma unroll
    for (int j8 = 0; j8 < 4; ++j8) {
        float4 f0 = {0, 0, 0, 0}, f1 = {0, 0, 0, 0};
        if (vld) {
            f0 = *reinterpret_cast<const float4*>(X + (size_t)n * 128 + k0 + j8 * 8);
            f1 = *reinterpret_cast<const float4*>(X + (size_t)n * 128 + k0 + j8 * 8 + 4);
        }
        float xv[8] = {f0.x * s, f0.y * s, f0.z * s, f0.w * s,
                       f1.x * s, f1.y * s, f1.z * s, f1.w * s};
        u32 o[4];
        #pragma unroll
        for (int q = 0; q < 4; ++q) {
            float lo = h2f(f2h(xv[q * 2]));
            float hi = h2f(f2h(xv[q * 2 + 1]));
            ss += lo * lo + hi * hi;
            o[q] = pack2h(xv[q * 2], xv[q * 2 + 1]);
        }
        int byte = ((nl * 128 + k0 + j8 * 8) * 2) ^ ((nl & 7) << 4);
        *reinterpret_cast<uint4*>((char*)xt + byte) = *reinterpret_cast<uint4*>(o);
    }
    xsqp[nl * 4 + part] = ss;
    __syncthreads();

    const int wid = threadIdx.x >> 6;
    const int lane = threadIdx.x & 63;
    const int lrow = lane & 15;
    const int lk8 = (lane >> 4) * 8;

    f32x4 acc[7] = {};
    #pragma unroll
    for (int ks = 0; ks < 4; ++ks) {
        int row = wid * 16 + lrow;
        int byte = ((row * 128 + ks * 32 + lk8) * 2) ^ ((row & 7) << 4);
        half8 afrag = *reinterpret_cast<const half8*>((const char*)xt + byte);
        #pragma unroll
        for (int nn = 0; nn < 7; ++nn) {
            int colr = nn * 16 + lrow;
            int bb = ((colr * 128 + ks * 32 + lk8) * 2) ^ ((colr & 7) << 4);
            half8 bfrag = *reinterpret_cast<const half8*>((const char*)ct + bb);
            acc[nn] = __builtin_amdgcn_mfma_f32_16x16x32_f16(afrag, bfrag, acc[nn], 0, 0, 0);
        }
    }

    float xs[4];
    #pragma unroll
    for (int j = 0; j < 4; ++j) {
        int row = wid * 16 + (lane >> 4) * 4 + j;
        xs[j] = xsqp[row * 4 + 0] + xsqp[row * 4 + 1] + xsqp[row * 4 + 2] + xsqp[row * 4 + 3];
    }
    __syncthreads();  // all waves done reading ct -> safe to overlay with dt

    #pragma unroll
    for (int nn = 0; nn < 7; ++nn) {
        int colr = nn * 16 + lrow;
        float cq = csqs[colr];
        #pragma unroll
        for (int j = 0; j < 4; ++j) {
            int row = wid * 16 + (lane >> 4) * 4 + j;
            float v = xs[j] - 2.f * acc[nn][j] + cq;
            dt[row * 112 + colr] = sqrtf(fmaxf(v, 0.f) + 1e-12f);
        }
    }
    __syncthreads();

    // segmented scan over sorted gids: 2 half-tiles x 100 cols (200 threads).
    // Segments spanning the half boundary emit two atomics (sum-correct).
    if (threadIdx.x < 200) {
        const int col = threadIdx.x % 100;
        const int r0 = (threadIdx.x / 100) * 32;
        float sum = 0.f;
        int cur = gidS[r0];
        for (int r = r0; r < r0 + 32; ++r) {
            int g = gidS[r];
            if (g != cur) {
                if (cur >= 0) atomicAdd(&psum[cur * NUM_CENTROID + col], sum);
                sum = 0.f;
                cur = g;
            }
            if (g >= 0) sum += dt[r * 112 + col];
        }
        if (cur >= 0) atomicAdd(&psum[cur * NUM_CENTROID + col], sum);
    }
}

// ---------------------------------------------------------------------------
// Final FC. Graph node-counts via binary search on sorted gid (no histogram).
// Thread t -> (g = t>>1, cls = t&1).
// ---------------------------------------------------------------------------
__global__ __launch_bounds__(256) void fc_kernel(
    const float* __restrict__ psum, const int* __restrict__ gid,
    const float* __restrict__ fc_w, const float* __restrict__ fc_b,
    float* __restrict__ out, int N)
{
    const int g = threadIdx.x >> 1;
    const int cls = threadIdx.x & 1;
    int lo = 0, hi = N;
    while (lo < hi) { int mid = (lo + hi) >> 1; if (gid[mid] < g) lo = mid + 1; else hi = mid; }
    const int start = lo;
    hi = N;
    while (lo < hi) { int mid = (lo + hi) >> 1; if (gid[mid] < g + 1) lo = mid + 1; else hi = mid; }
    float cnt = fmaxf((float)(lo - start), 1.0f);
    float o = 0.f;
    for (int c = 0; c < NUM_CENTROID; ++c)
        o += psum[g * NUM_CENTROID + c] * fc_w[c * 2 + cls];
    out[g * 2 + cls] = fc_b[cls] + o / cnt;
}

// ---------------------------------------------------------------------------
// Host launch
// ---------------------------------------------------------------------------
static const int W1OFF_H[6] = {0, 2048, 4096, 8192, 16384, 32768};
static const int W2OFF_H[6] = {0, 1024, 2048, 6144, 10240, 26624};

extern "C" void kernel_launch(void* const* d_in, const int* in_sizes, int n_in,
                              void* d_out, int out_size, void* d_ws, size_t ws_size,
                              hipStream_t stream) {
    const float* features = (const float*)d_in[0];
    const int*   src      = (const int*)d_in[1];
    const int*   dst      = (const int*)d_in[2];
    const int*   gid      = (const int*)d_in[3];
    const float* gamma    = (const float*)d_in[4];
    const float* beta     = (const float*)d_in[5];
    const float *W1[6], *b1[6], *W2[6], *b2[6];
    for (int i = 0; i < 6; ++i) {
        W1[i] = (const float*)d_in[6 + 4 * i];
        b1[i] = (const float*)d_in[7 + 4 * i];
        W2[i] = (const float*)d_in[8 + 4 * i];
        b2[i] = (const float*)d_in[9 + 4 * i];
    }
    const float* centroids = (const float*)d_in[30];
    const float* fc_w      = (const float*)d_in[31];
    const float* fc_b      = (const float*)d_in[32];

    const int N = N_NODES, E = N_EDGES;

    char* p = (char*)d_ws;
    size_t off = 0;
    auto alloc = [&](size_t bytes) {
        void* r = p + off;
        off += (bytes + 255) & ~(size_t)255;
        return r;
    };

    float* X0bn = (float*)alloc((size_t)N * IN_FEAT * 4);
    char* xz0 = p + off;
    float* XL[6];
    const int LCC[6] = {32, 32, 64, 64, 128, 128};
    for (int i = 0; i < 6; ++i) XL[i] = (float*)alloc((size_t)N * LCC[i] * 4);
    size_t xzbytes = (size_t)((p + off) - xz0);

    u16* Uh = (u16*)alloc((size_t)N * 128 * 2);
    u16* Vh = (u16*)alloc((size_t)N * 128 * 2);

    int*   row_off = (int*)alloc((size_t)(N + 1) * 4);
    int*   csr_src = (int*)alloc((size_t)E * 4);
    int*   csr_dst = (int*)alloc((size_t)E * 4);
    float* deg_inv = (float*)alloc((size_t)N * 4);
    u16*   w1img   = (u16*)alloc((size_t)W1TOT * 2);
    u16*   w2img   = (u16*)alloc((size_t)W2TOT * 2);
    u16*   centimg = (u16*)alloc((size_t)CTOT * 2);
    float* csq     = (float*)alloc(112 * 4);

    char*  zero0   = (char*)(p + off);
    int*   counts  = (int*)alloc((size_t)N * 4);
    int*   cursor  = (int*)alloc((size_t)N * 4);
    float* bnacc   = (float*)alloc(64);
    float* psum    = (float*)alloc((size_t)N_GRAPHS * NUM_CENTROID * 4);
    size_t zbytes  = (size_t)((char*)(p + off) - zero0);

    (void)hipMemsetAsync(xz0, 0, xzbytes, stream);
    (void)hipMemsetAsync(zero0, 0, zbytes, stream);

    setup1_kernel<<<BN_BLKS + DSTH_BLKS, 256, 0, stream>>>(
        features, bnacc, dst, counts);
    scan_kernel<<<1, 1024, 0, stream>>>(counts, row_off, deg_inv, N);

    Setup2Args sa;
    sa.dst = dst; sa.src = src; sa.row_off = row_off; sa.cursor = cursor;
    sa.csr_src = csr_src; sa.csr_dst = csr_dst;
    sa.f = features; sa.acc = bnacc; sa.gamma = gamma; sa.beta = beta; sa.X0 = X0bn;
    for (int i = 0; i < 6; ++i) { sa.w1[i] = W1[i]; sa.w2[i] = W2[i]; }
    sa.cent = centroids; sa.w1img = w1img; sa.w2img = w2img;
    sa.centimg = centimg; sa.csq = csq;
    const int S2B = CSR_BLKS + BNN_BLKS + (PREP_TOT + 255) / 256;
    setup2_kernel<<<S2B, 256, 0, stream>>>(sa);

    const int NB = (N + 31) / 32;

    node_mfma_kernel<5, 32, 32><<<NB, 256, 0, stream>>>(
        X0bn, (const float*)nullptr, w1img + W1OFF_H[0], b1[0], Uh, Vh, N);
    edge_agg_kernel<32, 256><<<(E + 255) / 256, 256, 0, stream>>>(
        Uh, Vh, csr_src, csr_dst, w2img + W2OFF_H[0], b2[0], XL[0], E);

    node_mfma_kernel<32, 32, 32><<<NB, 256, 0, stream>>>(
        XL[0], deg_inv, w1img + W1OFF_H[1], b1[1], Uh, Vh, N);
    edge_agg_kernel<32, 256><<<(E + 255) / 256, 256, 0, stream>>>(
        Uh, Vh, csr_src, csr_dst, w2img + W2OFF_H[1], b2[1], XL[1], E);

    node_mfma_kernel<32, 32, 64><<<NB, 256, 0, stream>>>(
        XL[1], deg_inv, w1img + W1OFF_H[2], b1[2], Uh, Vh, N);
    edge_agg_kernel<64, 128><<<(E + 127) / 128, 256, 0, stream>>>(
        Uh, Vh, csr_src, csr_dst, w2img + W2OFF_H[2], b2[2], XL[2], E);

    node_mfma_kernel<64, 64, 64><<<NB, 256, 0, stream>>>(
        XL[2], deg_inv, w1img + W1OFF_H[3], b1[3], Uh, Vh, N);
    edge_agg_kernel<64, 128><<<(E + 127) / 128, 256, 0, stream>>>(
        Uh, Vh, csr_src, csr_dst, w2img + W2OFF_H[3], b2[3], XL[3], E);

    node_mfma_kernel<64, 64, 128><<<NB, 256, 0, stream>>>(
        XL[3], deg_inv, w1img + W1OFF_H[4], b1[4], Uh, Vh, N);
    edge_agg_kernel<128, 64><<<(E + 63) / 64, 256, 0, stream>>>(
        Uh, Vh, csr_src, csr_dst, w2img + W2OFF_H[4], b2[4], XL[4], E);

    node_mfma_kernel<128, 128, 128><<<NB, 256, 0, stream>>>(
        XL[4], deg_inv, w1img + W1OFF_H[5], b1[5], Uh, Vh, N);
    edge_agg_kernel<128, 64><<<(E + 63) / 64, 256, 0, stream>>>(
        Uh, Vh, csr_src, csr_dst, w2img + W2OFF_H[5], b2[5], XL[5], E);

    dist_pool_kernel<<<(N + 63) / 64, 256, 0, stream>>>(
        XL[5], deg_inv, centimg, csq, gid, psum, N);
    fc_kernel<<<1, 256, 0, stream>>>(psum, gid, fc_w, fc_b, (float*)d_out, N);
}

// Round 10
// 533.187 us; speedup vs baseline: 1.0753x; 1.0284x over previous
//
#include <hip/hip_runtime.h>
#include <hip/hip_fp16.h>

// ---------------------------------------------------------------------------
// HyperbolicGNN: BN -> 6x EdgeConv -> centroid dist+pool (fused) -> FC
// fp16 datapath, f16 MFMA 16x16x32, fp32 accum.
// CSR build with ZERO global atomics (LDS histograms + rank scatter).
// X ping-pong buffers; zeroing fused into node_mfma (no 54MB memset).
// ---------------------------------------------------------------------------
#define N_NODES 30000
#define N_EDGES 480000
#define N_GRAPHS 128
#define IN_FEAT 5
#define NUM_CENTROID 100
#define BN_EPS 1e-5f

typedef unsigned int u32;
typedef unsigned short u16;

using half8 = __attribute__((ext_vector_type(8))) _Float16;
using h2    = __attribute__((ext_vector_type(2))) _Float16;
using f32x4 = __attribute__((ext_vector_type(4))) float;

__device__ __forceinline__ u16 f2h(float x) {
    return __half_as_ushort(__float2half_rn(x));
}
__device__ __forceinline__ float h2f(u16 h) {
    return __half2float(__ushort_as_half(h));
}
__device__ __forceinline__ u32 pack2h(float lo, float hi) {
    return (u32)f2h(lo) | ((u32)f2h(hi) << 16);
}

// ---------------------------------------------------------------------------
// hist: LDS-privatized dst histogram + local edge ranks (no global atomics)
//   120 blocks = 60 edge-chunks x 2 dst-halves, 1024 thr, 60KB LDS each.
//   + bn_stats (shfl-reduce) in trailing blocks.
// ---------------------------------------------------------------------------
#define HCHUNKS 60
#define EPC 8000          // edges per chunk (60*8000 == 480000)
#define HIST_BLKS 120
#define BN1_BLKS 30       // 30*1024 >= 30000

__global__ __launch_bounds__(1024) void hist_kernel(
    const int* __restrict__ dst, int* __restrict__ rank_local,
    int* __restrict__ partial,
    const float* __restrict__ f, float* __restrict__ acc)
{
    const int b = blockIdx.x;
    if (b < HIST_BLKS) {
        __shared__ int lh[15000];
        const int chunk = b >> 1;
        const int nbase = (b & 1) * 15000;
        for (int i = threadIdx.x; i < 15000; i += 1024) lh[i] = 0;
        __syncthreads();
        const int e0 = chunk * EPC;
        for (int e = e0 + threadIdx.x; e < e0 + EPC; e += 1024) {
            int dl = dst[e] - nbase;
            if (dl >= 0 && dl < 15000) {
                int r = atomicAdd(&lh[dl], 1);   // LDS atomic (fast)
                rank_local[e] = r;
            }
        }
        __syncthreads();
        for (int i = threadIdx.x; i < 15000; i += 1024)
            partial[chunk * N_NODES + nbase + i] = lh[i];
    } else {
        int n = (b - HIST_BLKS) * 1024 + threadIdx.x;
        float q[10];
        #pragma unroll
        for (int k = 0; k < 10; ++k) q[k] = 0.f;
        if (n < N_NODES) {
            #pragma unroll
            for (int k = 0; k < IN_FEAT; ++k) {
                float v = f[n * IN_FEAT + k];
                q[k] = v;
                q[5 + k] = v * v;
            }
        }
        #pragma unroll
        for (int k = 0; k < 10; ++k) {
            #pragma unroll
            for (int o = 32; o > 0; o >>= 1)
                q[k] += __shfl_xor(q[k], o);
        }
        if ((threadIdx.x & 63) == 0) {
            #pragma unroll
            for (int k = 0; k < 10; ++k) atomicAdd(&acc[k], q[k]);
        }
    }
}

// ---------------------------------------------------------------------------
// colsum: per-node prefix over chunks (partial -> exclusive prefix in place,
// counts[n] = total). Coalesced across n for each chunk. + bn_norm.
// ---------------------------------------------------------------------------
#define COLSUM_BLKS 118
#define BNN_BLKS 586
__global__ __launch_bounds__(256) void colsum_kernel(
    int* __restrict__ partial, int* __restrict__ counts,
    const float* __restrict__ f, const float* __restrict__ acc,
    const float* __restrict__ gamma, const float* __restrict__ beta,
    float* __restrict__ X0)
{
    const int b = blockIdx.x;
    if (b < COLSUM_BLKS) {
        int n = b * 256 + threadIdx.x;
        if (n < N_NODES) {
            int run = 0;
            for (int c = 0; c < HCHUNKS; ++c) {
                int v = partial[c * N_NODES + n];
                partial[c * N_NODES + n] = run;
                run += v;
            }
            counts[n] = run;
        }
    } else {
        int i = (b - COLSUM_BLKS) * 256 + threadIdx.x;
        if (i < N_NODES * IN_FEAT) {
            int k = i % IN_FEAT;
            float mu = acc[k] / (float)N_NODES;
            float var = acc[5 + k] / (float)N_NODES - mu * mu;
            float sc = gamma[k] / sqrtf(var + BN_EPS);
            X0[i] = (f[i] - mu) * sc + beta[k];
        }
    }
}

// ---------------------------------------------------------------------------
// scan: row offsets + deg_inv (single block)
// ---------------------------------------------------------------------------
__global__ __launch_bounds__(1024) void scan_kernel(
    const int* __restrict__ counts, int* __restrict__ row_off,
    float* __restrict__ deg_inv, int N)
{
    __shared__ int s[1024];
    const int CH = 30;
    int t = threadIdx.x;
    int base = t * CH;
    int loc = 0;
    for (int j = 0; j < CH; ++j) {
        int i = base + j;
        if (i < N) loc += counts[i];
    }
    s[t] = loc;
    __syncthreads();
    for (int off = 1; off < 1024; off <<= 1) {
        int v = (t >= off) ? s[t - off] : 0;
        __syncthreads();
        s[t] += v;
        __syncthreads();
    }
    int run = s[t] - loc;
    for (int j = 0; j < CH; ++j) {
        int i = base + j;
        if (i < N) {
            int cv = counts[i];
            row_off[i] = run;
            run += cv;
            deg_inv[i] = 1.0f / fmaxf((float)cv, 1.0f);
        }
    }
    if (t == 1023) row_off[N] = s[1023];
}

// ---------------------------------------------------------------------------
// fill: atomic-free CSR scatter + megaprep (fp16 images, swizzled)
// ---------------------------------------------------------------------------
__constant__ __device__ const int LFIN[6] = {5, 32, 32, 64, 64, 128};
__constant__ __device__ const int LKD[6]  = {32, 32, 32, 64, 64, 128};
__constant__ __device__ const int LCD[6]  = {32, 32, 64, 64, 128, 128};
__constant__ __device__ const int W1OFF[6] = {0, 2048, 4096, 8192, 16384, 32768};
__constant__ __device__ const int W2OFF[6] = {0, 1024, 2048, 6144, 10240, 26624};
#define W1TOT 65536
#define W2TOT 43008
#define CTOT  14336  // 112*128
#define PREP_TOT (W1TOT + W2TOT + CTOT + 112)
#define CSR_BLKS 1875

struct FillArgs {
    const int* dst; const int* src; const int* row_off;
    const int* rank_local; const int* partial;
    int* csr_src; int* csr_dst;
    const float* w1[6]; const float* w2[6]; const float* cent;
    u16* w1img; u16* w2img; u16* centimg; float* csq;
};

__global__ __launch_bounds__(256) void fill_kernel(FillArgs a)
{
    const int b = blockIdx.x;
    if (b < CSR_BLKS) {
        int e = b * 256 + threadIdx.x;
        if (e < N_EDGES) {
            int d = a.dst[e];
            int slot = a.row_off[d] + a.partial[(e / EPC) * N_NODES + d] + a.rank_local[e];
            a.csr_src[slot] = a.src[e];
            a.csr_dst[slot] = d;
        }
        return;
    }
    int gid = (b - CSR_BLKS) * 256 + threadIdx.x;
    if (gid < W1TOT) {
        int l = 0;
        #pragma unroll
        for (int i = 1; i < 6; ++i) if (gid >= W1OFF[i]) l = i;
        int local = gid - W1OFF[l];
        int K = LKD[l], C = LCD[l], F = LFIN[l];
        int n = local / K, k = local % K;
        float v = 0.f;
        if (k < F) {
            if (n < C) v = a.w1[l][k * C + n] - a.w1[l][(F + k) * C + n];
            else       v = a.w1[l][(F + k) * C + (n - C)];
        }
        int byte = (local * 2) ^ ((n & 7) << 4);
        *(u16*)((char*)a.w1img + (size_t)W1OFF[l] * 2 + byte) = f2h(v);
        return;
    }
    int g2 = gid - W1TOT;
    if (g2 < W2TOT) {
        int l = 0;
        #pragma unroll
        for (int i = 1; i < 6; ++i) if (g2 >= W2OFF[i]) l = i;
        int local = g2 - W2OFF[l];
        int C = LCD[l];
        int n = local / C, k = local % C;
        float v = a.w2[l][k * C + n];
        int byte = (local * 2) ^ ((n & 7) << 4);
        *(u16*)((char*)a.w2img + (size_t)W2OFF[l] * 2 + byte) = f2h(v);
        return;
    }
    int g3 = g2 - W2TOT;
    if (g3 < CTOT) {
        int c = g3 / 128, d = g3 % 128;
        float v = (c < NUM_CENTROID) ? a.cent[c * 128 + d] : 0.f;
        int byte = (g3 * 2) ^ ((c & 7) << 4);
        *(u16*)((char*)a.centimg + byte) = f2h(v);
        return;
    }
    int c = g3 - CTOT;
    if (c < 112) {
        float s = 0.f;
        if (c < NUM_CENTROID) {
            for (int d = 0; d < 128; ++d) {
                float cv = h2f(f2h(a.cent[c * 128 + d]));
                s += cv * cv;
            }
        }
        a.csq[c] = s;
    }
}

// ---------------------------------------------------------------------------
// Node MFMA GEMM: [32 nodes] x [2C cols], fp16 in/out, fp32 accum.
// Also zeroes the next edge_agg's accumulation buffer (CZ wide) -- fused.
// ---------------------------------------------------------------------------
template <int FIN, int K, int C, int CZ>
__global__ __launch_bounds__(256) void node_mfma_kernel(
    const float* __restrict__ Xin, const float* __restrict__ scale,
    const u16* __restrict__ w1img, const float* __restrict__ b1,
    u16* __restrict__ U, u16* __restrict__ V,
    float* __restrict__ Xzero, int N)
{
    constexpr int COLS = 2 * C;
    __shared__ u16 wt[COLS * K];
    __shared__ u16 xt[32 * K];

    for (int i = threadIdx.x; i < COLS * K / 8; i += 256)
        reinterpret_cast<uint4*>(wt)[i] = reinterpret_cast<const uint4*>(w1img)[i];

    constexpr int DPT = K / 8;
    const int nl = threadIdx.x >> 3;
    const int part = threadIdx.x & 7;
    const int n = blockIdx.x * 32 + nl;
    const int k0 = part * DPT;
    const bool vld = (n < N);
    float s = 1.f;
    if (vld && scale) s = scale[n];

    float xv[DPT];
    if constexpr (FIN == K) {
        #pragma unroll
        for (int j4 = 0; j4 < DPT / 4; ++j4) {
            float4 f4 = {0, 0, 0, 0};
            if (vld) f4 = *reinterpret_cast<const float4*>(Xin + (size_t)n * FIN + k0 + j4 * 4);
            xv[j4 * 4 + 0] = f4.x * s; xv[j4 * 4 + 1] = f4.y * s;
            xv[j4 * 4 + 2] = f4.z * s; xv[j4 * 4 + 3] = f4.w * s;
        }
    } else {
        #pragma unroll
        for (int j = 0; j < DPT; ++j) {
            int k = k0 + j;
            xv[j] = (vld && k < FIN) ? Xin[(size_t)n * FIN + k] * s : 0.f;
        }
    }

    if constexpr (DPT == 4) {
        u32 o[2];
        o[0] = pack2h(xv[0], xv[1]);
        o[1] = pack2h(xv[2], xv[3]);
        int byte = ((nl * K + k0) * 2) ^ ((nl & 7) << 4);
        *reinterpret_cast<uint2*>((char*)xt + byte) = *reinterpret_cast<uint2*>(o);
    } else {
        #pragma unroll
        for (int j8 = 0; j8 < DPT / 8; ++j8) {
            u32 o[4];
            #pragma unroll
            for (int q = 0; q < 4; ++q)
                o[q] = pack2h(xv[j8 * 8 + q * 2], xv[j8 * 8 + q * 2 + 1]);
            int byte = ((nl * K + k0 + j8 * 8) * 2) ^ ((nl & 7) << 4);
            *reinterpret_cast<uint4*>((char*)xt + byte) = *reinterpret_cast<uint4*>(o);
        }
    }

    // fused zeroing of the buffer the coming edge_agg accumulates into
    if constexpr (CZ > 0) {
        constexpr int V4 = CZ / 4;
        const float4 z4 = {0.f, 0.f, 0.f, 0.f};
        for (int i = threadIdx.x; i < 32 * V4; i += 256) {
            int row = i / V4, c4 = i % V4;
            int nz = blockIdx.x * 32 + row;
            if (nz < N)
                reinterpret_cast<float4*>(Xzero + (size_t)nz * CZ)[c4] = z4;
        }
    }
    __syncthreads();

    constexpr int NT = COLS / 16;
    constexpr int NPW = NT / 4;   // 1, 2, 4
    constexpr int KS = K / 32;

    const int wid = threadIdx.x >> 6;
    const int lane = threadIdx.x & 63;
    const int lrow = lane & 15;
    const int lk8 = (lane >> 4) * 8;

    f32x4 acc[2][NPW] = {};

    #pragma unroll
    for (int ks = 0; ks < KS; ++ks) {
        half8 afrag[2];
        #pragma unroll
        for (int m = 0; m < 2; ++m) {
            int row = m * 16 + lrow;
            int byte = ((row * K + ks * 32 + lk8) * 2) ^ ((row & 7) << 4);
            afrag[m] = *reinterpret_cast<const half8*>((const char*)xt + byte);
        }
        #pragma unroll
        for (int nn = 0; nn < NPW; ++nn) {
            int colr = (wid * NPW + nn) * 16 + lrow;
            int byte = ((colr * K + ks * 32 + lk8) * 2) ^ ((colr & 7) << 4);
            half8 bfrag = *reinterpret_cast<const half8*>((const char*)wt + byte);
            #pragma unroll
            for (int m = 0; m < 2; ++m)
                acc[m][nn] = __builtin_amdgcn_mfma_f32_16x16x32_f16(
                    afrag[m], bfrag, acc[m][nn], 0, 0, 0);
        }
    }

    #pragma unroll
    for (int nn = 0; nn < NPW; ++nn) {
        int colr = (wid * NPW + nn) * 16 + lrow;
        float bias = (colr < C) ? b1[colr] : 0.f;
        #pragma unroll
        for (int m = 0; m < 2; ++m) {
            #pragma unroll
            for (int j = 0; j < 4; ++j) {
                int row = m * 16 + (lane >> 4) * 4 + j;
                int node = blockIdx.x * 32 + row;
                if (node < N) {
                    float z = acc[m][nn][j] + bias;
                    if (colr < C) U[(size_t)node * C + colr] = f2h(z);
                    else          V[(size_t)node * C + colr - C] = f2h(z);
                }
            }
        }
    }
}

// ---------------------------------------------------------------------------
// Fused edge GEMM + segmented reduction. W2 fragments in registers.
// ---------------------------------------------------------------------------
template <int C, int ET>
__global__ __launch_bounds__(256, 4) void edge_agg_kernel(
    const u16* __restrict__ U, const u16* __restrict__ V,
    const int* __restrict__ csr_src, const int* __restrict__ csr_dst,
    const u16* __restrict__ w2img, const float* __restrict__ b2,
    float* __restrict__ Xout, int E)
{
    constexpr int PAD = 2;
    __shared__ u16 at[ET * (C + PAD)];
    __shared__ int dstid[ET];

    constexpr int MT = ET / 16;
    constexpr int NT = C / 16;
    constexpr int WN = (NT < 4) ? NT : 4;
    constexpr int WM = 4 / WN;
    constexpr int MPW = MT / WM;
    constexpr int NPW = NT / WN;
    constexpr int KS = C / 32;

    const int wid = threadIdx.x >> 6;
    const int lane = threadIdx.x & 63;
    const int wn = wid % WN;
    const int wm = wid / WN;
    const int lrow = lane & 15;
    const int lk8 = (lane >> 4) * 8;

    half8 bfrag[NPW][KS];
    #pragma unroll
    for (int n = 0; n < NPW; ++n) {
        int col = (wn * NPW + n) * 16 + lrow;
        #pragma unroll
        for (int ks = 0; ks < KS; ++ks) {
            int byte = ((col * C + ks * 32 + lk8) * 2) ^ ((col & 7) << 4);
            bfrag[n][ks] = *reinterpret_cast<const half8*>((const char*)w2img + byte);
        }
    }

    constexpr int TPE = 256 / ET;
    const int e_loc = threadIdx.x / TPE;
    const int part  = threadIdx.x % TPE;
    const int k0 = part * 32;
    const int e = blockIdx.x * ET + e_loc;
    const bool valid = (e < E);
    const int dn = valid ? csr_dst[e] : 0;
    const int sn = valid ? csr_src[e] : 0;
    if (part == 0) dstid[e_loc] = valid ? dn : -1;

    const h2 zz = {(_Float16)0.f, (_Float16)0.f};
    const u16* Ur = U + (size_t)dn * C + k0;
    const u16* Vr = V + (size_t)sn * C + k0;
    #pragma unroll
    for (int j = 0; j < 4; ++j) {
        uint4 uu = {0, 0, 0, 0}, vv = {0, 0, 0, 0};
        if (valid) {
            uu = *reinterpret_cast<const uint4*>(Ur + j * 8);
            vv = *reinterpret_cast<const uint4*>(Vr + j * 8);
        }
        h2 o[4];
        const h2* ua = reinterpret_cast<const h2*>(&uu);
        const h2* va = reinterpret_cast<const h2*>(&vv);
        #pragma unroll
        for (int q = 0; q < 4; ++q)
            o[q] = __builtin_elementwise_max(ua[q] + va[q], zz);
        int byte = ((e_loc * C + k0 + j * 8) * 2) ^ ((e_loc & 7) << 4);
        *reinterpret_cast<uint4*>((char*)at + byte) = *reinterpret_cast<const uint4*>(o);
    }
    __syncthreads();

    f32x4 acc[MPW][NPW] = {};

    #pragma unroll
    for (int ks = 0; ks < KS; ++ks) {
        half8 afrag[MPW];
        #pragma unroll
        for (int m = 0; m < MPW; ++m) {
            int row = (wm * MPW + m) * 16 + lrow;
            int byte = ((row * C + ks * 32 + lk8) * 2) ^ ((row & 7) << 4);
            afrag[m] = *reinterpret_cast<const half8*>((const char*)at + byte);
        }
        #pragma unroll
        for (int m = 0; m < MPW; ++m)
            #pragma unroll
            for (int n = 0; n < NPW; ++n)
                acc[m][n] = __builtin_amdgcn_mfma_f32_16x16x32_f16(
                    afrag[m], bfrag[n][ks], acc[m][n], 0, 0, 0);
    }
    __syncthreads();

    #pragma unroll
    for (int m = 0; m < MPW; ++m) {
        #pragma unroll
        for (int n = 0; n < NPW; ++n) {
            int col = (wn * NPW + n) * 16 + lrow;
            float bb = b2[col];
            #pragma unroll
            for (int j = 0; j < 4; ++j) {
                int row = (wm * MPW + m) * 16 + (lane >> 4) * 4 + j;
                at[row * (C + PAD) + col] = f2h(fmaxf(acc[m][n][j] + bb, 0.f));
            }
        }
    }
    __syncthreads();

    constexpr int EPS = ET * C / 256;  // == 32
    const int col = threadIdx.x & (C - 1);
    const int e0 = (threadIdx.x / C) * EPS;
    float sum = 0.f;
    int cur = dstid[e0];
    #pragma unroll 4
    for (int ee = e0; ee < e0 + EPS; ++ee) {
        int d = dstid[ee];
        if (d != cur) {
            if (cur >= 0) atomicAdd(&Xout[(size_t)cur * C + col], sum);
            sum = 0.f;
            cur = d;
        }
        sum += h2f(at[ee * (C + PAD) + col]);
    }
    if (cur >= 0) atomicAdd(&Xout[(size_t)cur * C + col], sum);
}

// ---------------------------------------------------------------------------
// Fused centroid-distance + per-graph pooling.
// ---------------------------------------------------------------------------
__global__ __launch_bounds__(256) void dist_pool_kernel(
    const float* __restrict__ X, const float* __restrict__ scale,
    const u16* __restrict__ centimg, const float* __restrict__ csq,
    const int* __restrict__ gid, float* __restrict__ psum, int N)
{
    __shared__ char smem[46784];
    u16* ct = (u16*)smem;
    u16* xt = (u16*)(smem + 28672);
    float* xsqp = (float*)(smem + 45056);   // [64][4]
    float* csqs = (float*)(smem + 46080);   // [112]
    int* gidS   = (int*)(smem + 46528);     // [64]
    float* dt   = (float*)smem;             // [64][112], overlays ct

    for (int i = threadIdx.x; i < 112 * 128 / 8; i += 256)
        reinterpret_cast<uint4*>(ct)[i] = reinterpret_cast<const uint4*>(centimg)[i];
    if (threadIdx.x < 112) csqs[threadIdx.x] = csq[threadIdx.x];
    if (threadIdx.x < 64) {
        int n = blockIdx.x * 64 + threadIdx.x;
        gidS[threadIdx.x] = (n < N) ? gid[n] : -1;
    }

    const int nl = threadIdx.x >> 2;
    const int part = threadIdx.x & 3;
    const int n = blockIdx.x * 64 + nl;
    const int k0 = part * 32;
    const bool vld = (n < N);
    const float s = vld ? scale[n] : 0.f;

    float ss = 0.f;
    #pragma unroll
    for (int j8 = 0; j8 < 4; ++j8) {
        float4 f0 = {0, 0, 0, 0}, f1 = {0, 0, 0, 0};
        if (vld) {
            f0 = *reinterpret_cast<const float4*>(X + (size_t)n * 128 + k0 + j8 * 8);
            f1 = *reinterpret_cast<const float4*>(X + (size_t)n * 128 + k0 + j8 * 8 + 4);
        }
        float xv[8] = {f0.x * s, f0.y * s, f0.z * s, f0.w * s,
                       f1.x * s, f1.y * s, f1.z * s, f1.w * s};
        u32 o[4];
        #pragma unroll
        for (int q = 0; q < 4; ++q) {
            float lo = h2f(f2h(xv[q * 2]));
            float hi = h2f(f2h(xv[q * 2 + 1]));
            ss += lo * lo + hi * hi;
            o[q] = pack2h(xv[q * 2], xv[q * 2 + 1]);
        }
        int byte = ((nl * 128 + k0 + j8 * 8) * 2) ^ ((nl & 7) << 4);
        *reinterpret_cast<uint4*>((char*)xt + byte) = *reinterpret_cast<uint4*>(o);
    }
    xsqp[nl * 4 + part] = ss;
    __syncthreads();

    const int wid = threadIdx.x >> 6;
    const int lane = threadIdx.x & 63;
    const int lrow = lane & 15;
    const int lk8 = (lane >> 4) * 8;

    f32x4 acc[7] = {};
    #pragma unroll
    for (int ks = 0; ks < 4; ++ks) {
        int row = wid * 16 + lrow;
        int byte = ((row * 128 + ks * 32 + lk8) * 2) ^ ((row & 7) << 4);
        half8 afrag = *reinterpret_cast<const half8*>((const char*)xt + byte);
        #pragma unroll
        for (int nn = 0; nn < 7; ++nn) {
            int colr = nn * 16 + lrow;
            int bb = ((colr * 128 + ks * 32 + lk8) * 2) ^ ((colr & 7) << 4);
            half8 bfrag = *reinterpret_cast<const half8*>((const char*)ct + bb);
            acc[nn] = __builtin_amdgcn_mfma_f32_16x16x32_f16(afrag, bfrag, acc[nn], 0, 0, 0);
        }
    }

    float xs[4];
    #pragma unroll
    for (int j = 0; j < 4; ++j) {
        int row = wid * 16 + (lane >> 4) * 4 + j;
        xs[j] = xsqp[row * 4 + 0] + xsqp[row * 4 + 1] + xsqp[row * 4 + 2] + xsqp[row * 4 + 3];
    }
    __syncthreads();  // all waves done reading ct -> safe to overlay with dt

    #pragma unroll
    for (int nn = 0; nn < 7; ++nn) {
        int colr = nn * 16 + lrow;
        float cq = csqs[colr];
        #pragma unroll
        for (int j = 0; j < 4; ++j) {
            int row = wid * 16 + (lane >> 4) * 4 + j;
            float v = xs[j] - 2.f * acc[nn][j] + cq;
            dt[row * 112 + colr] = sqrtf(fmaxf(v, 0.f) + 1e-12f);
        }
    }
    __syncthreads();

    // segmented scan: 2 half-tiles x 100 cols (200 threads), 32 rows each
    if (threadIdx.x < 200) {
        const int col = threadIdx.x % 100;
        const int r0 = (threadIdx.x / 100) * 32;
        float sum = 0.f;
        int cur = gidS[r0];
        for (int r = r0; r < r0 + 32; ++r) {
            int g = gidS[r];
            if (g != cur) {
                if (cur >= 0) atomicAdd(&psum[cur * NUM_CENTROID + col], sum);
                sum = 0.f;
                cur = g;
            }
            if (g >= 0) sum += dt[r * 112 + col];
        }
        if (cur >= 0) atomicAdd(&psum[cur * NUM_CENTROID + col], sum);
    }
}

// ---------------------------------------------------------------------------
// Final FC. Graph node-counts via binary search on sorted gid.
// ---------------------------------------------------------------------------
__global__ __launch_bounds__(256) void fc_kernel(
    const float* __restrict__ psum, const int* __restrict__ gid,
    const float* __restrict__ fc_w, const float* __restrict__ fc_b,
    float* __restrict__ out, int N)
{
    const int g = threadIdx.x >> 1;
    const int cls = threadIdx.x & 1;
    int lo = 0, hi = N;
    while (lo < hi) { int mid = (lo + hi) >> 1; if (gid[mid] < g) lo = mid + 1; else hi = mid; }
    const int start = lo;
    hi = N;
    while (lo < hi) { int mid = (lo + hi) >> 1; if (gid[mid] < g + 1) lo = mid + 1; else hi = mid; }
    float cnt = fmaxf((float)(lo - start), 1.0f);
    float o = 0.f;
    for (int c = 0; c < NUM_CENTROID; ++c)
        o += psum[g * NUM_CENTROID + c] * fc_w[c * 2 + cls];
    out[g * 2 + cls] = fc_b[cls] + o / cnt;
}

// ---------------------------------------------------------------------------
// Host launch
// ---------------------------------------------------------------------------
static const int W1OFF_H[6] = {0, 2048, 4096, 8192, 16384, 32768};
static const int W2OFF_H[6] = {0, 1024, 2048, 6144, 10240, 26624};

extern "C" void kernel_launch(void* const* d_in, const int* in_sizes, int n_in,
                              void* d_out, int out_size, void* d_ws, size_t ws_size,
                              hipStream_t stream) {
    const float* features = (const float*)d_in[0];
    const int*   src      = (const int*)d_in[1];
    const int*   dst      = (const int*)d_in[2];
    const int*   gid      = (const int*)d_in[3];
    const float* gamma    = (const float*)d_in[4];
    const float* beta     = (const float*)d_in[5];
    const float *W1[6], *b1[6], *W2[6], *b2[6];
    for (int i = 0; i < 6; ++i) {
        W1[i] = (const float*)d_in[6 + 4 * i];
        b1[i] = (const float*)d_in[7 + 4 * i];
        W2[i] = (const float*)d_in[8 + 4 * i];
        b2[i] = (const float*)d_in[9 + 4 * i];
    }
    const float* centroids = (const float*)d_in[30];
    const float* fc_w      = (const float*)d_in[31];
    const float* fc_b      = (const float*)d_in[32];

    const int N = N_NODES, E = N_EDGES;

    char* p = (char*)d_ws;
    size_t off = 0;
    auto alloc = [&](size_t bytes) {
        void* r = p + off;
        off += (bytes + 255) & ~(size_t)255;
        return r;
    };

    float* X0bn = (float*)alloc((size_t)N * IN_FEAT * 4);
    float* XA   = (float*)alloc((size_t)N * 128 * 4);
    float* XB   = (float*)alloc((size_t)N * 128 * 4);
    u16*   Uh   = (u16*)alloc((size_t)N * 128 * 2);
    u16*   Vh   = (u16*)alloc((size_t)N * 128 * 2);

    int*   row_off    = (int*)alloc((size_t)(N + 1) * 4);
    int*   csr_src    = (int*)alloc((size_t)E * 4);
    int*   csr_dst    = (int*)alloc((size_t)E * 4);
    float* deg_inv    = (float*)alloc((size_t)N * 4);
    int*   counts     = (int*)alloc((size_t)N * 4);
    int*   rank_local = (int*)alloc((size_t)E * 4);
    int*   partial    = (int*)alloc((size_t)HCHUNKS * N * 4);
    u16*   w1img      = (u16*)alloc((size_t)W1TOT * 2);
    u16*   w2img      = (u16*)alloc((size_t)W2TOT * 2);
    u16*   centimg    = (u16*)alloc((size_t)CTOT * 2);
    float* csq        = (float*)alloc(112 * 4);

    char*  zero0 = (char*)(p + off);
    float* bnacc = (float*)alloc(64);
    float* psum  = (float*)alloc((size_t)N_GRAPHS * NUM_CENTROID * 4);
    size_t zbytes = (size_t)((char*)(p + off) - zero0);

    (void)hipMemsetAsync(zero0, 0, zbytes, stream);

    hist_kernel<<<HIST_BLKS + BN1_BLKS, 1024, 0, stream>>>(
        dst, rank_local, partial, features, bnacc);
    colsum_kernel<<<COLSUM_BLKS + BNN_BLKS, 256, 0, stream>>>(
        partial, counts, features, bnacc, gamma, beta, X0bn);
    scan_kernel<<<1, 1024, 0, stream>>>(counts, row_off, deg_inv, N);

    FillArgs fa;
    fa.dst = dst; fa.src = src; fa.row_off = row_off;
    fa.rank_local = rank_local; fa.partial = partial;
    fa.csr_src = csr_src; fa.csr_dst = csr_dst;
    for (int i = 0; i < 6; ++i) { fa.w1[i] = W1[i]; fa.w2[i] = W2[i]; }
    fa.cent = centroids; fa.w1img = w1img; fa.w2img = w2img;
    fa.centimg = centimg; fa.csq = csq;
    fill_kernel<<<CSR_BLKS + (PREP_TOT + 255) / 256, 256, 0, stream>>>(fa);

    const int NB = (N + 31) / 32;

    // L0: in X0bn -> out XA (zeroed here)
    node_mfma_kernel<5, 32, 32, 32><<<NB, 256, 0, stream>>>(
        X0bn, (const float*)nullptr, w1img + W1OFF_H[0], b1[0], Uh, Vh, XA, N);
    edge_agg_kernel<32, 256><<<(E + 255) / 256, 256, 0, stream>>>(
        Uh, Vh, csr_src, csr_dst, w2img + W2OFF_H[0], b2[0], XA, E);

    // L1: in XA -> out XB
    node_mfma_kernel<32, 32, 32, 32><<<NB, 256, 0, stream>>>(
        XA, deg_inv, w1img + W1OFF_H[1], b1[1], Uh, Vh, XB, N);
    edge_agg_kernel<32, 256><<<(E + 255) / 256, 256, 0, stream>>>(
        Uh, Vh, csr_src, csr_dst, w2img + W2OFF_H[1], b2[1], XB, E);

    // L2: in XB -> out XA
    node_mfma_kernel<32, 32, 64, 64><<<NB, 256, 0, stream>>>(
        XB, deg_inv, w1img + W1OFF_H[2], b1[2], Uh, Vh, XA, N);
    edge_agg_kernel<64, 128><<<(E + 127) / 128, 256, 0, stream>>>(
        Uh, Vh, csr_src, csr_dst, w2img + W2OFF_H[2], b2[2], XA, E);

    // L3: in XA -> out XB
    node_mfma_kernel<64, 64, 64, 64><<<NB, 256, 0, stream>>>(
        XA, deg_inv, w1img + W1OFF_H[3], b1[3], Uh, Vh, XB, N);
    edge_agg_kernel<64, 128><<<(E + 127) / 128, 256, 0, stream>>>(
        Uh, Vh, csr_src, csr_dst, w2img + W2OFF_H[3], b2[3], XB, E);

    // L4: in XB -> out XA
    node_mfma_kernel<64, 64, 128, 128><<<NB, 256, 0, stream>>>(
        XB, deg_inv, w1img + W1OFF_H[4], b1[4], Uh, Vh, XA, N);
    edge_agg_kernel<128, 64><<<(E + 63) / 64, 256, 0, stream>>>(
        Uh, Vh, csr_src, csr_dst, w2img + W2OFF_H[4], b2[4], XA, E);

    // L5: in XA -> out XB
    node_mfma_kernel<128, 128, 128, 128><<<NB, 256, 0, stream>>>(
        XA, deg_inv, w1img + W1OFF_H[5], b1[5], Uh, Vh, XB, N);
    edge_agg_kernel<128, 64><<<(E + 63) / 64, 256, 0, stream>>>(
        Uh, Vh, csr_src, csr_dst, w2img + W2OFF_H[5], b2[5], XB, E);

    dist_pool_kernel<<<(N + 63) / 64, 256, 0, stream>>>(
        XB, deg_inv, centimg, csq, gid, psum, N);
    fc_kernel<<<1, 256, 0, stream>>>(psum, gid, fc_w, fc_b, (float*)d_out, N);
}